// Round 4
// baseline (222.350 us; speedup 1.0000x reference)
//
#include <hip/hip_runtime.h>

// SNN conv layer: 3x3x16->64 conv (SAME) on 512x512 NHWC + old_potentials,
// threshold 1.0 -> (spikes, reset potentials).
// R5: bf16 implicit-GEMM via mfma_f32_16x16x32_bf16 (93.5us kernel).
// R6: A=weights/co, B=pixels swap -> dwordx4 epilogue (~78us).
// R7: entry-prefetch + TY=4 + prepacked weights + NT stores: NEUTRAL (~81us).
// R8: persistent pipelined blocks, raw barriers: NEUTRAL (<83us).
//   Three schedules, same time => the common cost is the LDS staging
//   structure itself (global->reg->pack->LDS->barrier->ds_read), m233-style,
//   for data that is L2/L3-resident anyway (input 8.5MB bf16, weights 19KB;
//   FETCH_SIZE 42MB < 84MB ideal reads proves L3 is serving reads).
// R9: NO LDS, NO barriers, NO bounds checks in the hot kernel.
//   Setup kernel pre-converts input -> zero-padded bf16 [514][514][16] in
//   d_ws (512MiB, per the 536.9MB poison fill) and pre-packs weights bf16
//   [64][152]. Main kernel: wave = 16px x 64co; 4 oldp dwordx4 + 5 A-frag
//   loads (L2/L3) + double-buffered weight frags (L2-hot) + 20 MFMA +
//   8 dwordx4 stores. Fully independent waves -> continuous memory issue
//   (the property that lets fillBuffer hit 6.7 TB/s at 9% occupancy).

#define H 512
#define W 512
#define CI 16
#define CO 64
#define PW 514               // padded width/height
#define PAD_PX (PW * PW)     // padded pixel count
#define KS 152               // weight k-stride in elements (304B rows)
#define W_OFF_U16 0          // weights at d_ws byte 0 (19456 B)
#define IN_OFF_U16 32768     // padded input at d_ws byte 65536 (16B aligned)

typedef float v4f __attribute__((ext_vector_type(4)));
typedef float f32x4 __attribute__((ext_vector_type(4)));
typedef short short8 __attribute__((ext_vector_type(8)));
typedef unsigned int uint4v __attribute__((ext_vector_type(4)));

__device__ __forceinline__ unsigned int pack2bf(float f0, float f1) {
    // round-to-nearest-even bf16 truncation of two floats, packed
    unsigned u0 = __builtin_bit_cast(unsigned, f0);
    unsigned u1 = __builtin_bit_cast(unsigned, f1);
    u0 = (u0 + 0x7FFFu + ((u0 >> 16) & 1u)) >> 16;
    u1 = (u1 + 0x7FFFu + ((u1 >> 16) & 1u)) >> 16;
    return u0 | (u1 << 16);
}

// ---- setup: blocks 0..(PAD_PX/256): pad+convert input f32 -> bf16
//            last block: pack w (3,3,16,64) f32 -> bf16 [n=64][k=KS]
__global__ void snn_setup(const float* __restrict__ in,
                          const float* __restrict__ w,
                          unsigned short* __restrict__ ws)
{
    const int tid = threadIdx.x;
    if (blockIdx.x == gridDim.x - 1) {
        // ---- weights
        unsigned int* wsu = (unsigned int*)(ws + W_OFF_U16);
        const int n  = tid & 63;
        const int kq = tid >> 6;                 // 0..3, 36 k-values each
        #pragma unroll
        for (int kk = 0; kk < 18; ++kk) {
            const int k = kq * 36 + kk * 2;
            const float f0 = w[k * CO + n];
            const float f1 = w[(k + 1) * CO + n];
            wsu[(n * KS + k) >> 1] = pack2bf(f0, f1);
        }
        if (kq == 3) {                           // zero k = 144..151
            #pragma unroll
            for (int i = 0; i < 4; ++i)
                wsu[((n * KS + 144) >> 1) + i] = 0u;
        }
        return;
    }
    // ---- padded input pixel
    const int p = blockIdx.x * 256 + tid;
    if (p >= PAD_PX) return;
    const int py = p / PW, px = p - py * PW;
    uint4v pk0 = (uint4v)0u, pk1 = (uint4v)0u;
    if (py >= 1 && py <= H && px >= 1 && px <= W) {
        const v4f* q = (const v4f*)(in + ((py - 1) * W + (px - 1)) * CI);
        v4f a = q[0], b = q[1], c = q[2], d = q[3];
        pk0 = (uint4v){pack2bf(a.x, a.y), pack2bf(a.z, a.w),
                       pack2bf(b.x, b.y), pack2bf(b.z, b.w)};
        pk1 = (uint4v){pack2bf(c.x, c.y), pack2bf(c.z, c.w),
                       pack2bf(d.x, d.y), pack2bf(d.z, d.w)};
    }
    uint4v* dst = (uint4v*)(ws + IN_OFF_U16 + p * CI);
    dst[0] = pk0;
    dst[1] = pk1;
}

__global__ __launch_bounds__(256, 3)
void snn_conv_mfma(const unsigned short* __restrict__ ws,
                   const float* __restrict__ oldp,
                   float* __restrict__ out_spk,
                   float* __restrict__ out_pot)
{
    const unsigned short* pin = ws + IN_OFF_U16;   // [PW][PW][16] bf16, padded
    const unsigned short* wsb = ws + W_OFF_U16;    // [64][KS] bf16

    const int tid  = threadIdx.x;
    const int bx   = blockIdx.x & 31;    // 32 x-tiles (16 px each)
    const int by   = blockIdx.x >> 5;    // 128 y-tiles (4 rows each)
    const int lane = tid & 63;
    const int wv   = tid >> 6;           // wave 0..3 -> one output row
    const int r    = lane & 15;          // pixel-within-16 (B/D) / co-within-16 (A)
    const int quad = lane >> 4;          // 0..3
    const int half = quad & 1;           // ci-half for pixel fragment
    const int tsel = quad >> 1;          // tap parity within K-step

    const int gy = by * 4 + wv;          // output row
    const int gx = bx * 16 + r;          // this lane's output col

    // ---- oldp loads first (longest latency, no dependencies)
    const int eb = (gy * W + gx) * CO + quad * 4;
    f32x4 oldv[4];
    #pragma unroll
    for (int nt = 0; nt < 4; ++nt)
        oldv[nt] = *(const f32x4*)(oldp + eb + nt * 16);

    // ---- all 5 A-fragments (pixels), straight from padded bf16 global.
    // tap t -> global pixel (gy + t/3 - 1, gx + t%3 - 1) == padded
    // pixel (gy + t/3, gx + t%3). 16B per lane, contiguous 512B per
    // quad-pair per instruction -> L2/L3-served.
    short8 af[5];
    #pragma unroll
    for (int ks5 = 0; ks5 < 5; ++ks5) {
        const int t = (ks5 == 4) ? 8 : (2 * ks5 + tsel);
        const int dy = t / 3, dx = t % 3;
        af[ks5] = *(const short8*)&pin[((gy + dy) * PW + (gx + dx)) * CI + half * 8];
    }
    {   // zero pad k=144..159 (B-side of the MFMA is the pixel operand)
        const short8 zero8 = {0, 0, 0, 0, 0, 0, 0, 0};
        if (quad >= 2) af[4] = zero8;
    }

    // ---- K loop: weights double-buffered from global (L2-hot: every block
    // reads the same 19KB; 64B-line coalesced across r).
    f32x4 acc[4] = {};
    short8 bf_a[4], bf_b[4];

    #pragma unroll
    for (int nt = 0; nt < 4; ++nt)
        bf_a[nt] = *(const short8*)&wsb[(nt * 16 + r) * KS + quad * 8];

    #pragma unroll
    for (int ks5 = 0; ks5 < 5; ++ks5) {
        short8* cur = (ks5 & 1) ? bf_b : bf_a;
        short8* nxt = (ks5 & 1) ? bf_a : bf_b;
        if (ks5 < 4) {
            const int koff = (ks5 == 3) ? (128 + half * 8)
                                        : ((ks5 + 1) * 32 + quad * 8);
            #pragma unroll
            for (int nt = 0; nt < 4; ++nt)
                nxt[nt] = *(const short8*)&wsb[(nt * 16 + r) * KS + koff];
        }
        // A = weights (M=co), B = pixels (N=pixel)
        #pragma unroll
        for (int nt = 0; nt < 4; ++nt)
            acc[nt] = __builtin_amdgcn_mfma_f32_16x16x32_bf16(
                cur[nt], af[ks5], acc[nt], 0, 0, 0);
    }

    // ---- epilogue: D col=lane&15 (pixel), row=quad*4+reg (co-within-16)
    // -> each f32x4 acc reg = 4 contiguous co -> dwordx4 stores.
    #pragma unroll
    for (int nt = 0; nt < 4; ++nt) {
        const int idx = eb + nt * 16;
        f32x4 np = acc[nt] + oldv[nt];
        f32x4 spk, pot;
        #pragma unroll
        for (int j = 0; j < 4; ++j) {
            const bool s = np[j] >= 1.0f;
            spk[j] = s ? 1.0f : 0.0f;
            pot[j] = s ? 0.0f : np[j];
        }
        *(f32x4*)(out_spk + idx) = spk;
        *(f32x4*)(out_pot + idx) = pot;
    }
}

extern "C" void kernel_launch(void* const* d_in, const int* in_sizes, int n_in,
                              void* d_out, int out_size, void* d_ws, size_t ws_size,
                              hipStream_t stream) {
    const float* in   = (const float*)d_in[0];     // (1,512,512,16)
    const float* w    = (const float*)d_in[1];     // (3,3,16,64)
    const float* oldp = (const float*)d_in[2];     // (1,512,512,64)
    float* out_spk = (float*)d_out;
    float* out_pot = out_spk + (size_t)H * W * CO;
    unsigned short* ws = (unsigned short*)d_ws;

    const int setup_grid = (PAD_PX + 255) / 256 + 1;   // +1 block for weights
    snn_setup<<<setup_grid, 256, 0, stream>>>(in, w, ws);

    const int grid = (W / 16) * (H / 4);               // 4096 blocks x 256 thr
    snn_conv_mfma<<<grid, 256, 0, stream>>>(ws, oldp, out_spk, out_pot);
}